// Round 3
// baseline (937.694 us; speedup 1.0000x reference)
//
#include <hip/hip_runtime.h>
#include <hip/hip_cooperative_groups.h>

namespace cg = cooperative_groups;

#define B_  16
#define T_  2048
#define L_  128
#define M_  256
#define H_  512
#define F_  1024
#define EPS 1e-5f

// LDS: As[32][36] + Bs[32][68] = 3328 floats = 13312 B
#define SMF 3328

// ---------------------------------------------------------------------------
// 32x64 fp32 GEMM tile, BK=32, TM=2, TN=4, 256 threads.
// amode: 0 = A row-major (lda)
//        1 = gather: A-row r -> x[b=r&15][T-1-(r>>4)][:]
//        2 = tree: A-row r -> vin[((r>>4)<<5)+16+(r&15)]; epilogue adds
//            Add[((r>>4)<<5)+(r&15)]
//        3 = rows 0..M-2 from A, row M-1 from Alast
// flags: 1 = +bias[c]
// ---------------------------------------------------------------------------
__device__ __forceinline__ void gemm_tile32(
    float* sm,
    const float* __restrict__ A, const float* __restrict__ Alast,
    const float* __restrict__ Bm, const float* __restrict__ bias,
    const float* __restrict__ Add, float* __restrict__ C,
    int M, int K, int lda, int ldb, int ldc,
    int flags, int amode, int bx, int by)
{
    constexpr int BM = 32, BN = 64, BK = 32, TM = 2, TN = 4;
    constexpr int LDA_S = BM + 4, LDB_S = BN + 4;
    float* As = sm;
    float* Bs = sm + BK * LDA_S;
    const int tid = threadIdx.x;
    const int tx  = tid % (BN / TN);
    const int ty  = tid / (BN / TN);
    const int row0 = by * BM, col0 = bx * BN;

    float acc[TM][TN] = {};

    for (int k0 = 0; k0 < K; k0 += BK) {
        // A tile: (32*32)/4 = 256 float4 -> 1 per thread
        {
            int arow = tid / (BK / 4), acg = tid % (BK / 4);
            int gr = row0 + arow, gk = k0 + acg * 4;
            float4 av = make_float4(0.f, 0.f, 0.f, 0.f);
            if (gr < M) {
                const float* p;
                if (amode == 1)
                    p = A + (long)((gr & 15) * T_ + (T_ - 1 - (gr >> 4))) * L_ + gk;
                else if (amode == 2)
                    p = A + (long)(((gr >> 4) << 5) + 16 + (gr & 15)) * lda + gk;
                else if (amode == 3 && gr == M - 1)
                    p = Alast + gk;
                else
                    p = A + (long)gr * lda + gk;
                av = *(const float4*)p;
            }
            As[(gk - k0 + 0) * LDA_S + arow] = av.x;
            As[(gk - k0 + 1) * LDA_S + arow] = av.y;
            As[(gk - k0 + 2) * LDA_S + arow] = av.z;
            As[(gk - k0 + 3) * LDA_S + arow] = av.w;
        }
        // B tile: (32*64)/4 = 512 float4 -> 2 per thread
#pragma unroll
        for (int f = tid; f < (BK * BN) / 4; f += 256) {
            int brow = f / (BN / 4), bcg = f % (BN / 4);
            float4 bv = *(const float4*)(Bm + (long)(k0 + brow) * ldb + col0 + bcg * 4);
            *(float4*)&Bs[brow * LDB_S + bcg * 4] = bv;
        }
        __syncthreads();
#pragma unroll
        for (int kk = 0; kk < BK; ++kk) {
            float ra[TM], rb[TN];
#pragma unroll
            for (int i = 0; i < TM; ++i) ra[i] = As[kk * LDA_S + ty * TM + i];
#pragma unroll
            for (int j = 0; j < TN; ++j) rb[j] = Bs[kk * LDB_S + tx * TN + j];
#pragma unroll
            for (int i = 0; i < TM; ++i)
#pragma unroll
                for (int j = 0; j < TN; ++j)
                    acc[i][j] = fmaf(ra[i], rb[j], acc[i][j]);
        }
        __syncthreads();
    }

#pragma unroll
    for (int i = 0; i < TM; ++i) {
        int r = row0 + ty * TM + i;
        if (r >= M) continue;
#pragma unroll
        for (int j = 0; j < TN; ++j) {
            int c = col0 + tx * TN + j;
            float v = acc[i][j];
            if (flags & 1) v += bias[c];
            if (amode == 2) v += Add[(long)(((r >> 4) << 5) + (r & 15)) * ldc + c];
            C[(long)r * ldc + c] = v;
        }
    }
}

// ---------------------------------------------------------------------------
// One cooperative kernel for the whole pipeline. 512 blocks x 256 threads
// (2 blocks/CU, guaranteed co-resident).
// ---------------------------------------------------------------------------
__global__ __launch_bounds__(256, 2) void fused(
    const float* __restrict__ x, const float* __restrict__ We,
    const float* __restrict__ be, const float* __restrict__ Wb,
    const float* __restrict__ A, const float* __restrict__ Wr,
    const float* __restrict__ br, const float* __restrict__ lng,
    const float* __restrict__ lnb, const float* __restrict__ W1,
    const float* __restrict__ b1, const float* __restrict__ W2,
    const float* __restrict__ b2, float* __restrict__ out,
    float* Wc, float* V0, float* V1,
    float* Ps0, float* Ps1, float* Ps2, float* Ps3,
    float* zn, float* hid)
{
    cg::grid_group grid = cg::this_grid();
    __shared__ float sm[SMF];
    const int nb = gridDim.x, bid = blockIdx.x, tid = threadIdx.x;

    // ---- S0: Wc = [We;be] @ Wb (129x512, K=256) [40 jobs]  ||  Ps0 = A*A [128]
    for (int j = bid; j < 168; j += nb) {
        if (j < 40)
            gemm_tile32(sm, We, be, Wb, nullptr, nullptr, Wc,
                        129, M_, M_, H_, H_, 0, 3, j % 8, j / 8);
        else {
            int s = j - 40;
            gemm_tile32(sm, A, nullptr, A, nullptr, nullptr, Ps0,
                        H_, H_, H_, H_, H_, 0, 0, s % 8, s / 8);
        }
    }
    grid.sync();

    // ---- S1: V0[k*16+b] = x[b][T-1-k]@Wc + bc (2048x512, K=128) [512]
    //          ||  Ps1 = Ps0^2 (=A^4) [128]
    for (int j = bid; j < 640; j += nb) {
        if (j < 512)
            gemm_tile32(sm, x, nullptr, Wc, Wc + 128 * H_, nullptr, V0,
                        2048, L_, L_, H_, H_, 1, 1, j % 8, j / 8);
        else {
            int s = j - 512;
            gemm_tile32(sm, Ps0, nullptr, Ps0, nullptr, nullptr, Ps1,
                        H_, H_, H_, H_, H_, 0, 0, s % 8, s / 8);
        }
    }
    grid.sync();

    // ---- tree levels l=1..7: V'_q = V_2q + V_{2q+1} @ A^(2^(l-1))
    // Power buffers: l uses {A,Ps0,Ps1,Ps2,Ps3,Ps0,Ps1}; during l=1..4 the
    // spare blocks square {Ps1,Ps2,Ps3,Ps0} -> {Ps2,Ps3,Ps0,Ps1}
    // (slot reuse is safe: Ps0(A^2) dead after l=2 stage, Ps1(A^4) after l=3).
    {
        const float* Puse[7] = {A, Ps0, Ps1, Ps2, Ps3, Ps0, Ps1};
        float* sqs[4] = {Ps1, Ps2, Ps3, Ps0};
        float* sqd[4] = {Ps2, Ps3, Ps0, Ps1};
        float* vin = V0;
        float* vout = V1;
        int Mr = 1024;
        for (int l = 1; l <= 7; ++l) {
            int rowTiles = (Mr + 31) / 32;
            int nC = rowTiles * 8;
            int nJ = nC + ((l <= 4) ? 128 : 0);
            for (int j = bid; j < nJ; j += nb) {
                if (j < nC)
                    gemm_tile32(sm, vin, nullptr, Puse[l - 1], nullptr, vin, vout,
                                Mr, H_, H_, H_, H_, 0, 2, j % 8, j / 8);
                else {
                    int s = j - nC;
                    gemm_tile32(sm, sqs[l - 1], nullptr, sqs[l - 1], nullptr,
                                nullptr, sqd[l - 1], H_, H_, H_, H_, H_,
                                0, 0, s % 8, s / 8);
                }
            }
            grid.sync();
            float* t = vin; vin = vout; vout = t;
            Mr >>= 1;
        }
        // h_T = rows 0..15 of vin (== V1)

        // ---- zln: z = h + x_last@Wr + br; LayerNorm -> zn  [16 jobs]
        for (int j = bid; j < 16; j += nb) {
            float* xl = sm;                    // [128]
            float* red1 = sm + 128;            // [4]
            float* red2 = sm + 136;            // [4]
            int b = j;
            if (tid < L_) xl[tid] = x[((size_t)b * T_ + (T_ - 1)) * L_ + tid];
            __syncthreads();
            int c0 = tid, c1 = tid + 256;
            float z0 = vin[b * H_ + c0] + br[c0];
            float z1 = vin[b * H_ + c1] + br[c1];
#pragma unroll 4
            for (int l = 0; l < L_; ++l) {
                float xv = xl[l];
                z0 = fmaf(xv, Wr[l * H_ + c0], z0);
                z1 = fmaf(xv, Wr[l * H_ + c1], z1);
            }
            float s1 = z0 + z1;
            float s2 = z0 * z0 + z1 * z1;
#pragma unroll
            for (int off = 32; off > 0; off >>= 1) {
                s1 += __shfl_down(s1, off, 64);
                s2 += __shfl_down(s2, off, 64);
            }
            int wid = tid >> 6, lane = tid & 63;
            if (lane == 0) { red1[wid] = s1; red2[wid] = s2; }
            __syncthreads();
            float S1 = red1[0] + red1[1] + red1[2] + red1[3];
            float S2 = red2[0] + red2[1] + red2[2] + red2[3];
            float mu  = S1 * (1.0f / H_);
            float var = S2 * (1.0f / H_) - mu * mu;
            float rs  = rsqrtf(var + EPS);
            zn[b * H_ + c0] = (z0 - mu) * rs * lng[c0] + lnb[c0];
            zn[b * H_ + c1] = (z1 - mu) * rs * lng[c1] + lnb[c1];
            __syncthreads();
        }
        grid.sync();
    }

    // ---- hid = relu(zn @ W1 + b1)  (16x1024, K=512)  [64 jobs, thread/output]
    for (int j = bid; j < 64; j += nb) {
        int b = j >> 2;
        int c = (j & 3) * 256 + tid;
        const float* zr = zn + b * H_;
        float a0 = 0.f, a1 = 0.f, a2 = 0.f, a3 = 0.f;
#pragma unroll 4
        for (int h = 0; h < H_; h += 4) {
            a0 = fmaf(zr[h + 0], W1[(long)(h + 0) * F_ + c], a0);
            a1 = fmaf(zr[h + 1], W1[(long)(h + 1) * F_ + c], a1);
            a2 = fmaf(zr[h + 2], W1[(long)(h + 2) * F_ + c], a2);
            a3 = fmaf(zr[h + 3], W1[(long)(h + 3) * F_ + c], a3);
        }
        float v = (a0 + a1) + (a2 + a3) + b1[c];
        hid[b * F_ + c] = fmaxf(v, 0.f);
    }
    grid.sync();

    // ---- out = hid @ W2 + b2  (16x512, K=1024)  [32 jobs, thread/output]
    for (int j = bid; j < 32; j += nb) {
        int b = j >> 1;
        int c = (j & 1) * 256 + tid;
        const float* hr = hid + b * F_;
        float a0 = 0.f, a1 = 0.f, a2 = 0.f, a3 = 0.f;
#pragma unroll 4
        for (int h = 0; h < F_; h += 4) {
            a0 = fmaf(hr[h + 0], W2[(long)(h + 0) * H_ + c], a0);
            a1 = fmaf(hr[h + 1], W2[(long)(h + 1) * H_ + c], a1);
            a2 = fmaf(hr[h + 2], W2[(long)(h + 2) * H_ + c], a2);
            a3 = fmaf(hr[h + 3], W2[(long)(h + 3) * H_ + c], a3);
        }
        out[b * H_ + c] = (a0 + a1) + (a2 + a3) + b2[c];
    }
}

// ---------------------------------------------------------------------------
extern "C" void kernel_launch(void* const* d_in, const int* in_sizes, int n_in,
                              void* d_out, int out_size, void* d_ws, size_t ws_size,
                              hipStream_t stream) {
    const float* x    = (const float*)d_in[0];
    const float* We   = (const float*)d_in[1];
    const float* be   = (const float*)d_in[2];
    const float* Wb   = (const float*)d_in[3];
    const float* Amat = (const float*)d_in[4];
    const float* Wr   = (const float*)d_in[5];
    const float* br   = (const float*)d_in[6];
    const float* lng  = (const float*)d_in[7];
    const float* lnb  = (const float*)d_in[8];
    const float* W1   = (const float*)d_in[9];
    const float* b1   = (const float*)d_in[10];
    const float* W2   = (const float*)d_in[11];
    const float* b2   = (const float*)d_in[12];
    float* out = (float*)d_out;

    float* ws  = (float*)d_ws;
    float* Wc  = ws;                         // 129 x 512
    float* V0  = Wc + 129 * H_;              // 2048 x 512
    float* V1  = V0 + 2048 * H_;             // 1024 x 512
    float* Ps0 = V1 + 1024 * H_;             // 512 x 512  (A^2, later A^32)
    float* Ps1 = Ps0 + H_ * H_;              // 512 x 512  (A^4, later A^64)
    float* Ps2 = Ps1 + H_ * H_;              // 512 x 512  (A^8)
    float* Ps3 = Ps2 + H_ * H_;              // 512 x 512  (A^16)
    float* zn  = Ps3 + H_ * H_;              // 16 x 512
    float* hid = zn + B_ * H_;               // 16 x 1024

    void* args[] = {
        (void*)&x, (void*)&We, (void*)&be, (void*)&Wb, (void*)&Amat,
        (void*)&Wr, (void*)&br, (void*)&lng, (void*)&lnb, (void*)&W1,
        (void*)&b1, (void*)&W2, (void*)&b2, (void*)&out,
        (void*)&Wc, (void*)&V0, (void*)&V1,
        (void*)&Ps0, (void*)&Ps1, (void*)&Ps2, (void*)&Ps3,
        (void*)&zn, (void*)&hid};
    hipLaunchCooperativeKernel((void*)fused, dim3(512), dim3(256), args, 0, stream);
}

// Round 4
// 391.988 us; speedup vs baseline: 2.3921x; 2.3921x over previous
//
#include <hip/hip_runtime.h>

#define B_  16
#define T_  2048
#define L_  128
#define M_  256
#define H_  512
#define F_  1024
#define EPS 1e-5f

// LDS: As[64][36] + Bs[64][68] = 6656 floats = 26624 B  (2 blocks/CU)
#define LDA_S 36
#define LDB_S 68
#define SMSZ (64 * LDA_S + 64 * LDB_S)

// ---------------------------------------------------------------------------
// A-operand load with source remap.
// amode: 0 = row-major(lda); 1 = gather x[b=r&15][T-1-(r>>4)][:];
//        2 = tree (row -> vin[((r>>4)<<5)+16+(r&15)]);
//        3 = rows 0..M-2 from A, row M-1 from Alast
// ---------------------------------------------------------------------------
__device__ __forceinline__ float4 load_a4(const float* __restrict__ A,
                                          const float* __restrict__ Alast,
                                          int M, int lda, int amode,
                                          int gr, int gk) {
    float4 av = make_float4(0.f, 0.f, 0.f, 0.f);
    if (gr < M) {
        const float* p;
        if (amode == 1)
            p = A + (long)((gr & 15) * T_ + (T_ - 1 - (gr >> 4))) * L_ + gk;
        else if (amode == 2)
            p = A + (long)(((gr >> 4) << 5) + 16 + (gr & 15)) * lda + gk;
        else if (amode == 3 && gr == M - 1)
            p = Alast + gk;
        else
            p = A + (long)gr * lda + gk;
        av = *(const float4*)p;
    }
    return av;
}

// ---------------------------------------------------------------------------
// 32x64 tile GEMM, BK=64, TM=2 TN=4, 256 threads, reg-prefetch pipeline.
// flags: 1 = +bias[c].  amode==2 epilogue adds Add[((r>>4)<<5)+(r&15)].
// ---------------------------------------------------------------------------
__device__ __forceinline__ void gemm_tile(
    float* sm,
    const float* __restrict__ A, const float* __restrict__ Alast,
    const float* __restrict__ Bm, const float* __restrict__ bias,
    const float* __restrict__ Add, float* __restrict__ C,
    int M, int K, int lda, int ldb, int ldc,
    int flags, int amode, int bx, int by)
{
    constexpr int BM = 32, BN = 64, BK = 64, TM = 2, TN = 4;
    float* As = sm;                    // [64][36] transposed A tile
    float* Bs = sm + BK * LDA_S;       // [64][68]
    const int tid = threadIdx.x;
    const int tx = tid & 15;           // BN/TN = 16
    const int ty = tid >> 4;           // 0..15
    const int row0 = by * BM, col0 = bx * BN;

    float4 pa[2], pb[4];
#pragma unroll
    for (int t = 0; t < 2; ++t) {
        int f = tid + t * 256;
        pa[t] = load_a4(A, Alast, M, lda, amode, row0 + (f >> 4), (f & 15) * 4);
    }
#pragma unroll
    for (int t = 0; t < 4; ++t) {
        int f = tid + t * 256;
        pb[t] = *(const float4*)(Bm + (long)(f >> 4) * ldb + col0 + (f & 15) * 4);
    }

    float acc[TM][TN] = {};

    for (int k0 = 0; k0 < K; k0 += BK) {
        __syncthreads();               // prior compute done reading LDS
#pragma unroll
        for (int t = 0; t < 2; ++t) {
            int f = tid + t * 256;
            int arow = f >> 4, kk = (f & 15) * 4;
            As[(kk + 0) * LDA_S + arow] = pa[t].x;
            As[(kk + 1) * LDA_S + arow] = pa[t].y;
            As[(kk + 2) * LDA_S + arow] = pa[t].z;
            As[(kk + 3) * LDA_S + arow] = pa[t].w;
        }
#pragma unroll
        for (int t = 0; t < 4; ++t) {
            int f = tid + t * 256;
            *(float4*)&Bs[(f >> 4) * LDB_S + (f & 15) * 4] = pb[t];
        }
        __syncthreads();
        int kn = k0 + BK;
        if (kn < K) {                  // prefetch next tiles; in flight during FMAs
#pragma unroll
            for (int t = 0; t < 2; ++t) {
                int f = tid + t * 256;
                pa[t] = load_a4(A, Alast, M, lda, amode, row0 + (f >> 4), kn + (f & 15) * 4);
            }
#pragma unroll
            for (int t = 0; t < 4; ++t) {
                int f = tid + t * 256;
                pb[t] = *(const float4*)(Bm + (long)(kn + (f >> 4)) * ldb + col0 + (f & 15) * 4);
            }
        }
#pragma unroll
        for (int kk = 0; kk < BK; ++kk) {
            float ra[TM], rb[TN];
#pragma unroll
            for (int i = 0; i < TM; ++i) ra[i] = As[kk * LDA_S + ty * TM + i];
#pragma unroll
            for (int j = 0; j < TN; ++j) rb[j] = Bs[kk * LDB_S + tx * TN + j];
#pragma unroll
            for (int i = 0; i < TM; ++i)
#pragma unroll
                for (int j = 0; j < TN; ++j)
                    acc[i][j] = fmaf(ra[i], rb[j], acc[i][j]);
        }
    }

#pragma unroll
    for (int i = 0; i < TM; ++i) {
        int r = row0 + ty * TM + i;
        if (r >= M) continue;
#pragma unroll
        for (int j = 0; j < TN; ++j) {
            int c = col0 + tx * TN + j;
            float v = acc[i][j];
            if (flags & 1) v += bias[c];
            if (amode == 2) v += Add[(long)(((r >> 4) << 5) + (r & 15)) * ldc + c];
            C[(long)r * ldc + c] = v;
        }
    }
}

// Dual-job kernel: blocks [0,nA) run job A; blocks [nA, ...) compute
// SqOut = SqL @ SqR (512x512x512) for the A-power chain.
__global__ __launch_bounds__(256) void dual(
    const float* A, const float* Alast, const float* Bm, const float* bias,
    const float* Add, float* C, int M, int K, int lda, int ldb, int ldc,
    int flags, int amode, int nbxA, int nA,
    const float* SqL, const float* SqR, float* SqOut)
{
    __shared__ float sm[SMSZ];
    int j = blockIdx.x;
    if (j < nA)
        gemm_tile(sm, A, Alast, Bm, bias, Add, C, M, K, lda, ldb, ldc,
                  flags, amode, j % nbxA, j / nbxA);
    else {
        int s = j - nA;
        gemm_tile(sm, SqL, nullptr, SqR, nullptr, nullptr, SqOut,
                  H_, H_, H_, H_, H_, 0, 0, s % 8, s / 8);
    }
}

// ---------------------------------------------------------------------------
// Fused: radix-4 final combine + z + LayerNorm + MLP layer 1 chunk.
// grid = 64: b = bid>>2 (batch), cc = bid&3 (256-col chunk of F_).
// h[c] = V[b][c] + sum_q V[(q+1)*16+b] @ Pq[c],  Pq = {A^32, A^64, A^96}
// ---------------------------------------------------------------------------
__global__ __launch_bounds__(256) void zmlp1(
    const float* __restrict__ V, const float* __restrict__ x,
    const float* __restrict__ Wr, const float* __restrict__ br,
    const float* __restrict__ lng, const float* __restrict__ lnb,
    const float* __restrict__ P32, const float* __restrict__ P64,
    const float* __restrict__ P96,
    const float* __restrict__ W1, const float* __restrict__ b1,
    float* __restrict__ hid)
{
    __shared__ float xl[L_];
    __shared__ float vrow[3][H_];
    __shared__ float znrow[H_];
    __shared__ float red1[4], red2[4];
    const int b = blockIdx.x >> 2, cc = blockIdx.x & 3, tid = threadIdx.x;

    if (tid < L_) xl[tid] = x[((size_t)b * T_ + (T_ - 1)) * L_ + tid];
#pragma unroll
    for (int q = 0; q < 3; ++q)
        for (int i = tid; i < H_; i += 256)
            vrow[q][i] = V[(long)((q + 1) * 16 + b) * H_ + i];
    __syncthreads();

    const float* Pq[3] = {P32, P64, P96};
    float z[2];
#pragma unroll
    for (int jj = 0; jj < 2; ++jj) {
        int c = tid + jj * 256;
        float s = V[(long)b * H_ + c] + br[c];
#pragma unroll 4
        for (int l = 0; l < L_; ++l) s = fmaf(xl[l], Wr[l * H_ + c], s);
#pragma unroll
        for (int q = 0; q < 3; ++q) {
            const float* P = Pq[q];
            const float* vr = vrow[q];
            float a0 = 0.f, a1 = 0.f, a2 = 0.f, a3 = 0.f;
            for (int k = 0; k < H_; k += 4) {
                a0 = fmaf(vr[k + 0], P[(long)(k + 0) * H_ + c], a0);
                a1 = fmaf(vr[k + 1], P[(long)(k + 1) * H_ + c], a1);
                a2 = fmaf(vr[k + 2], P[(long)(k + 2) * H_ + c], a2);
                a3 = fmaf(vr[k + 3], P[(long)(k + 3) * H_ + c], a3);
            }
            s += (a0 + a1) + (a2 + a3);
        }
        z[jj] = s;
    }

    float s1 = z[0] + z[1];
    float s2 = z[0] * z[0] + z[1] * z[1];
#pragma unroll
    for (int off = 32; off > 0; off >>= 1) {
        s1 += __shfl_down(s1, off, 64);
        s2 += __shfl_down(s2, off, 64);
    }
    int wid = tid >> 6, lane = tid & 63;
    if (lane == 0) { red1[wid] = s1; red2[wid] = s2; }
    __syncthreads();
    float S1 = red1[0] + red1[1] + red1[2] + red1[3];
    float S2 = red2[0] + red2[1] + red2[2] + red2[3];
    float mu  = S1 * (1.0f / H_);
    float var = S2 * (1.0f / H_) - mu * mu;
    float rs  = rsqrtf(var + EPS);
#pragma unroll
    for (int jj = 0; jj < 2; ++jj) {
        int c = tid + jj * 256;
        znrow[c] = (z[jj] - mu) * rs * lng[c] + lnb[c];
    }
    __syncthreads();

    // MLP layer 1: hid[b][cc*256+tid]
    {
        int c = cc * 256 + tid;
        float a0 = 0.f, a1 = 0.f, a2 = 0.f, a3 = 0.f;
        for (int h = 0; h < H_; h += 4) {
            a0 = fmaf(znrow[h + 0], W1[(long)(h + 0) * F_ + c], a0);
            a1 = fmaf(znrow[h + 1], W1[(long)(h + 1) * F_ + c], a1);
            a2 = fmaf(znrow[h + 2], W1[(long)(h + 2) * F_ + c], a2);
            a3 = fmaf(znrow[h + 3], W1[(long)(h + 3) * F_ + c], a3);
        }
        float v = (a0 + a1) + (a2 + a3) + b1[c];
        hid[(long)b * F_ + c] = fmaxf(v, 0.f);
    }
}

// MLP layer 2: grid = 32 (b = bid>>1, cc = bid&1)
__global__ __launch_bounds__(256) void mlp2(
    const float* __restrict__ hid, const float* __restrict__ W2,
    const float* __restrict__ b2, float* __restrict__ out)
{
    __shared__ float hs[F_];
    const int b = blockIdx.x >> 1, cc = blockIdx.x & 1, tid = threadIdx.x;
    ((float4*)hs)[tid] = ((const float4*)(hid + (long)b * F_))[tid];
    __syncthreads();
    int c = cc * 256 + tid;
    float a0 = 0.f, a1 = 0.f, a2 = 0.f, a3 = 0.f;
    for (int h = 0; h < F_; h += 4) {
        a0 = fmaf(hs[h + 0], W2[(long)(h + 0) * H_ + c], a0);
        a1 = fmaf(hs[h + 1], W2[(long)(h + 1) * H_ + c], a1);
        a2 = fmaf(hs[h + 2], W2[(long)(h + 2) * H_ + c], a2);
        a3 = fmaf(hs[h + 3], W2[(long)(h + 3) * H_ + c], a3);
    }
    out[(long)b * H_ + c] = (a0 + a1) + (a2 + a3) + b2[c];
}

// ---------------------------------------------------------------------------
extern "C" void kernel_launch(void* const* d_in, const int* in_sizes, int n_in,
                              void* d_out, int out_size, void* d_ws, size_t ws_size,
                              hipStream_t stream) {
    const float* x    = (const float*)d_in[0];
    const float* We   = (const float*)d_in[1];
    const float* be   = (const float*)d_in[2];
    const float* Wb   = (const float*)d_in[3];
    const float* Amat = (const float*)d_in[4];
    const float* Wr   = (const float*)d_in[5];
    const float* br   = (const float*)d_in[6];
    const float* lng  = (const float*)d_in[7];
    const float* lnb  = (const float*)d_in[8];
    const float* W1   = (const float*)d_in[9];
    const float* b1   = (const float*)d_in[10];
    const float* W2   = (const float*)d_in[11];
    const float* b2   = (const float*)d_in[12];
    float* out = (float*)d_out;

    float* ws  = (float*)d_ws;
    float* Wc  = ws;                         // 129 x 512
    float* V0  = Wc + 129 * H_;              // 2048 x 512
    float* V1  = V0 + 2048 * H_;             // 1024 x 512
    float* P2  = V1 + 1024 * H_;             // A^2
    float* P4  = P2 + H_ * H_;               // A^4
    float* P8  = P4 + H_ * H_;               // A^8
    float* P16 = P8 + H_ * H_;               // A^16
    float* P32 = P16 + H_ * H_;              // A^32
    float* P64 = P32 + H_ * H_;              // A^64
    float* P96 = P64 + H_ * H_;              // A^96
    float* hid = P96 + H_ * H_;              // 16 x 1024

    // K0: Wc = [We;be]@Wb (129x512,K=256) [40] || A^2 [128]
    dual<<<168, 256, 0, stream>>>(We, be, Wb, nullptr, nullptr, Wc,
                                  129, M_, M_, H_, H_, 0, 3, 8, 40,
                                  Amat, Amat, P2);
    // K1: V0 = gather(x)@Wc + bc (2048x512,K=128) [512] || A^4 [128]
    dual<<<640, 256, 0, stream>>>(x, nullptr, Wc, Wc + 128 * H_, nullptr, V0,
                                  2048, L_, L_, H_, H_, 1, 1, 8, 512,
                                  P2, P2, P4);
    // K2 (l1): V1 = comb(V0, A), 1024 rows [256] || A^8 [128]
    dual<<<384, 256, 0, stream>>>(V0, nullptr, Amat, nullptr, V0, V1,
                                  1024, H_, H_, H_, H_, 0, 2, 8, 256,
                                  P4, P4, P8);
    // K3 (l2): V0 = comb(V1, A^2), 512 rows [128] || A^16 [128]
    dual<<<256, 256, 0, stream>>>(V1, nullptr, P2, nullptr, V1, V0,
                                  512, H_, H_, H_, H_, 0, 2, 8, 128,
                                  P8, P8, P16);
    // K4 (l3): V1 = comb(V0, A^4), 256 rows [64] || A^32 [128]
    dual<<<192, 256, 0, stream>>>(V0, nullptr, P4, nullptr, V0, V1,
                                  256, H_, H_, H_, H_, 0, 2, 8, 64,
                                  P16, P16, P32);
    // K5 (l4): V0 = comb(V1, A^8), 128 rows [32] || A^64 [128]
    dual<<<160, 256, 0, stream>>>(V1, nullptr, P8, nullptr, V1, V0,
                                  128, H_, H_, H_, H_, 0, 2, 8, 32,
                                  P32, P32, P64);
    // K6 (l5): V1 = comb(V0, A^16), 64 rows (4 nodes) [16] || A^96 = A^32*A^64 [128]
    dual<<<144, 256, 0, stream>>>(V0, nullptr, P16, nullptr, V0, V1,
                                  64, H_, H_, H_, H_, 0, 2, 8, 16,
                                  P32, P64, P96);
    // K7: radix-4 final + z + LN + MLP1
    zmlp1<<<64, 256, 0, stream>>>(V1, x, Wr, br, lng, lnb, P32, P64, P96,
                                  W1, b1, hid);
    // K8: MLP2
    mlp2<<<32, 256, 0, stream>>>(hid, W2, b2, out);
}

// Round 5
// 284.835 us; speedup vs baseline: 3.2921x; 1.3762x over previous
//
#include <hip/hip_runtime.h>

#define B_  16
#define T_  2048
#define L_  128
#define M_  256
#define H_  512
#define F_  1024
#define EPS 1e-5f

// LDS: As[64][36] + Bs[64][68] = 6656 floats = 26624 B  (2 blocks/CU)
#define LDA_S 36
#define LDB_S 68
#define SMSZ (64 * LDA_S + 64 * LDB_S)

// ---------------------------------------------------------------------------
// A-operand load with source remap.
// amode: 0 = row-major(lda); 1 = gather x[b=r&15][T-1-(r>>4)][:];
//        2 = tree (row -> vin[((r>>4)<<5)+16+(r&15)]);
//        3 = rows 0..M-2 from A, row M-1 from Alast
// ---------------------------------------------------------------------------
__device__ __forceinline__ float4 load_a4(const float* __restrict__ A,
                                          const float* __restrict__ Alast,
                                          int M, int lda, int amode,
                                          int gr, int gk) {
    float4 av = make_float4(0.f, 0.f, 0.f, 0.f);
    if (gr < M) {
        const float* p;
        if (amode == 1)
            p = A + (long)((gr & 15) * T_ + (T_ - 1 - (gr >> 4))) * L_ + gk;
        else if (amode == 2)
            p = A + (long)(((gr >> 4) << 5) + 16 + (gr & 15)) * lda + gk;
        else if (amode == 3 && gr == M - 1)
            p = Alast + gk;
        else
            p = A + (long)gr * lda + gk;
        av = *(const float4*)p;
    }
    return av;
}

// ---------------------------------------------------------------------------
// 32x64 tile GEMM, BK=64, TM=2 TN=4, 256 threads, reg-prefetch pipeline.
// flags: 1 = +bias[c].  amode==2 epilogue adds Add[((r>>4)<<5)+(r&15)].
// ---------------------------------------------------------------------------
__device__ __forceinline__ void gemm_tile(
    float* sm,
    const float* __restrict__ A, const float* __restrict__ Alast,
    const float* __restrict__ Bm, const float* __restrict__ bias,
    const float* __restrict__ Add, float* __restrict__ C,
    int M, int K, int lda, int ldb, int ldc,
    int flags, int amode, int bx, int by)
{
    constexpr int BM = 32, BN = 64, BK = 64, TM = 2, TN = 4;
    float* As = sm;                    // [64][36] transposed A tile
    float* Bs = sm + BK * LDA_S;       // [64][68]
    const int tid = threadIdx.x;
    const int tx = tid & 15;           // BN/TN = 16
    const int ty = tid >> 4;           // 0..15
    const int row0 = by * BM, col0 = bx * BN;

    float4 pa[2], pb[4];
#pragma unroll
    for (int t = 0; t < 2; ++t) {
        int f = tid + t * 256;
        pa[t] = load_a4(A, Alast, M, lda, amode, row0 + (f >> 4), (f & 15) * 4);
    }
#pragma unroll
    for (int t = 0; t < 4; ++t) {
        int f = tid + t * 256;
        pb[t] = *(const float4*)(Bm + (long)(f >> 4) * ldb + col0 + (f & 15) * 4);
    }

    float acc[TM][TN] = {};

    for (int k0 = 0; k0 < K; k0 += BK) {
        __syncthreads();               // prior compute done reading LDS
#pragma unroll
        for (int t = 0; t < 2; ++t) {
            int f = tid + t * 256;
            int arow = f >> 4, kk = (f & 15) * 4;
            As[(kk + 0) * LDA_S + arow] = pa[t].x;
            As[(kk + 1) * LDA_S + arow] = pa[t].y;
            As[(kk + 2) * LDA_S + arow] = pa[t].z;
            As[(kk + 3) * LDA_S + arow] = pa[t].w;
        }
#pragma unroll
        for (int t = 0; t < 4; ++t) {
            int f = tid + t * 256;
            *(float4*)&Bs[(f >> 4) * LDB_S + (f & 15) * 4] = pb[t];
        }
        __syncthreads();
        int kn = k0 + BK;
        if (kn < K) {                  // prefetch next tiles; in flight during FMAs
#pragma unroll
            for (int t = 0; t < 2; ++t) {
                int f = tid + t * 256;
                pa[t] = load_a4(A, Alast, M, lda, amode, row0 + (f >> 4), kn + (f & 15) * 4);
            }
#pragma unroll
            for (int t = 0; t < 4; ++t) {
                int f = tid + t * 256;
                pb[t] = *(const float4*)(Bm + (long)(kn + (f >> 4)) * ldb + col0 + (f & 15) * 4);
            }
        }
#pragma unroll
        for (int kk = 0; kk < BK; ++kk) {
            float ra[TM], rb[TN];
#pragma unroll
            for (int i = 0; i < TM; ++i) ra[i] = As[kk * LDA_S + ty * TM + i];
#pragma unroll
            for (int j = 0; j < TN; ++j) rb[j] = Bs[kk * LDB_S + tx * TN + j];
#pragma unroll
            for (int i = 0; i < TM; ++i)
#pragma unroll
                for (int j = 0; j < TN; ++j)
                    acc[i][j] = fmaf(ra[i], rb[j], acc[i][j]);
        }
    }

#pragma unroll
    for (int i = 0; i < TM; ++i) {
        int r = row0 + ty * TM + i;
        if (r >= M) continue;
#pragma unroll
        for (int j = 0; j < TN; ++j) {
            int c = col0 + tx * TN + j;
            float v = acc[i][j];
            if (flags & 1) v += bias[c];
            if (amode == 2) v += Add[(long)(((r >> 4) << 5) + (r & 15)) * ldc + c];
            C[(long)r * ldc + c] = v;
        }
    }
}

// Dual-job kernel: blocks [0,nA) run job A; blocks [nA, ...) compute
// SqOut = SqL @ SqR (512x512x512) for the A-power chain.
__global__ __launch_bounds__(256) void dual(
    const float* A, const float* Alast, const float* Bm, const float* bias,
    const float* Add, float* C, int M, int K, int lda, int ldb, int ldc,
    int flags, int amode, int nbxA, int nA,
    const float* SqL, const float* SqR, float* SqOut)
{
    __shared__ float sm[SMSZ];
    int j = blockIdx.x;
    if (j < nA)
        gemm_tile(sm, A, Alast, Bm, bias, Add, C, M, K, lda, ldb, ldc,
                  flags, amode, j % nbxA, j / nbxA);
    else {
        int s = j - nA;
        gemm_tile(sm, SqL, nullptr, SqR, nullptr, nullptr, SqOut,
                  H_, H_, H_, H_, H_, 0, 0, s % 8, s / 8);
    }
}

// ---------------------------------------------------------------------------
// Tail split-K GEMM: BM=16, BN=64, BK=64, 256 threads, 4 outputs/thread.
// MODE 0: z-GEMM  A = [V1nodes1..3 | x_last] (K=1664), B = [P32;P64;P96;Wr]
// MODE 1: MLP1    A = zn (16x512),  B = W1 (512x1024)
// MODE 2: MLP2    A = hid (16x1024), B = W2 (1024x512)
// Writes partials: parts[kc][16][LDC], kc = blockIdx.x / nbx.
// ---------------------------------------------------------------------------
#define TLDA 20
#define TLDB 68
#define TSM (64 * TLDA + 64 * TLDB)

template <int MODE>
__device__ __forceinline__ float4 tail_a4(const float* __restrict__ Asrc,
                                          const float* __restrict__ x,
                                          int b, int gk) {
    if (MODE == 0) {
        int seg = gk >> 9;
        if (seg < 3)
            return *(const float4*)(Asrc + (long)((seg + 1) * 16 + b) * H_ + (gk & 511));
        return *(const float4*)(x + ((long)b * T_ + (T_ - 1)) * L_ + (gk - 1536));
    } else if (MODE == 1) {
        return *(const float4*)(Asrc + (long)b * H_ + gk);
    } else {
        return *(const float4*)(Asrc + (long)b * F_ + gk);
    }
}

template <int MODE>
__device__ __forceinline__ float4 tail_b4(const float* __restrict__ P32,
                                          const float* __restrict__ P64,
                                          const float* __restrict__ P96,
                                          const float* __restrict__ WrB,
                                          int kr, int c) {
    if (MODE == 0) {
        const float* p;
        if (kr < 512)       p = P32 + (long)kr * H_;
        else if (kr < 1024) p = P64 + (long)(kr - 512) * H_;
        else if (kr < 1536) p = P96 + (long)(kr - 1024) * H_;
        else                p = WrB + (long)(kr - 1536) * H_;
        return *(const float4*)(p + c);
    } else if (MODE == 1) {
        return *(const float4*)(WrB + (long)kr * F_ + c);
    } else {
        return *(const float4*)(WrB + (long)kr * H_ + c);
    }
}

template <int MODE>
__global__ __launch_bounds__(256) void tailgemm(
    const float* __restrict__ Asrc, const float* __restrict__ x,
    const float* __restrict__ P32, const float* __restrict__ P64,
    const float* __restrict__ P96, const float* __restrict__ WrB,
    float* __restrict__ parts, int nbx, int kLen)
{
    constexpr int LDC = (MODE == 1) ? F_ : H_;
    __shared__ float sm[TSM];
    float* As = sm;                    // [64][20] transposed (A[k][row])
    float* Bs = sm + 64 * TLDA;        // [64][68]
    const int tid = threadIdx.x;
    const int tx = tid & 15, ty = tid >> 4;      // ty = row 0..15
    const int kc = blockIdx.x / nbx;
    const int col0 = (blockIdx.x % nbx) * 64;
    const int kOff = kc * kLen;

    float4 pa, pb[4];
    {
        int gk = kOff + (tid & 15) * 4;
        pa = tail_a4<MODE>(Asrc, x, tid >> 4, gk);
#pragma unroll
        for (int t = 0; t < 4; ++t) {
            int f = tid + t * 256;
            pb[t] = tail_b4<MODE>(P32, P64, P96, WrB, kOff + (f >> 4), col0 + (f & 15) * 4);
        }
    }

    float acc[4] = {};
    for (int k0 = kOff; k0 < kOff + kLen; k0 += 64) {
        __syncthreads();
        {
            int arow = tid >> 4, kk = (tid & 15) * 4;
            As[(kk + 0) * TLDA + arow] = pa.x;
            As[(kk + 1) * TLDA + arow] = pa.y;
            As[(kk + 2) * TLDA + arow] = pa.z;
            As[(kk + 3) * TLDA + arow] = pa.w;
        }
#pragma unroll
        for (int t = 0; t < 4; ++t) {
            int f = tid + t * 256;
            *(float4*)&Bs[(f >> 4) * TLDB + (f & 15) * 4] = pb[t];
        }
        __syncthreads();
        int kn = k0 + 64;
        if (kn < kOff + kLen) {
            pa = tail_a4<MODE>(Asrc, x, tid >> 4, kn + (tid & 15) * 4);
#pragma unroll
            for (int t = 0; t < 4; ++t) {
                int f = tid + t * 256;
                pb[t] = tail_b4<MODE>(P32, P64, P96, WrB, kn + (f >> 4), col0 + (f & 15) * 4);
            }
        }
#pragma unroll
        for (int kk = 0; kk < 64; ++kk) {
            float ra = As[kk * TLDA + ty];
            float4 rb = *(float4*)&Bs[kk * TLDB + tx * 4];
            acc[0] = fmaf(ra, rb.x, acc[0]);
            acc[1] = fmaf(ra, rb.y, acc[1]);
            acc[2] = fmaf(ra, rb.z, acc[2]);
            acc[3] = fmaf(ra, rb.w, acc[3]);
        }
    }

    float* dst = parts + (long)kc * 16 * LDC + (long)ty * LDC + col0 + tx * 4;
    *(float4*)dst = make_float4(acc[0], acc[1], acc[2], acc[3]);
}

// z = node0 + br + sum(zparts); LayerNorm -> zn.  grid=16 (one block / batch)
__global__ __launch_bounds__(256) void zlnred(
    const float* __restrict__ V1, const float* __restrict__ zparts,
    const float* __restrict__ br, const float* __restrict__ lng,
    const float* __restrict__ lnb, float* __restrict__ zn)
{
    __shared__ float red1[4], red2[4];
    const int b = blockIdx.x, tid = threadIdx.x;
    float z[2];
#pragma unroll
    for (int jj = 0; jj < 2; ++jj) {
        int c = tid + jj * 256;
        float s = V1[(long)b * H_ + c] + br[c];      // node0 row
#pragma unroll
        for (int kc = 0; kc < 13; ++kc)
            s += zparts[(long)kc * 16 * H_ + (long)b * H_ + c];
        z[jj] = s;
    }
    float s1 = z[0] + z[1];
    float s2 = z[0] * z[0] + z[1] * z[1];
#pragma unroll
    for (int off = 32; off > 0; off >>= 1) {
        s1 += __shfl_down(s1, off, 64);
        s2 += __shfl_down(s2, off, 64);
    }
    int wid = tid >> 6, lane = tid & 63;
    if (lane == 0) { red1[wid] = s1; red2[wid] = s2; }
    __syncthreads();
    float S1 = red1[0] + red1[1] + red1[2] + red1[3];
    float S2 = red2[0] + red2[1] + red2[2] + red2[3];
    float mu  = S1 * (1.0f / H_);
    float var = S2 * (1.0f / H_) - mu * mu;
    float rs  = rsqrtf(var + EPS);
#pragma unroll
    for (int jj = 0; jj < 2; ++jj) {
        int c = tid + jj * 256;
        zn[(long)b * H_ + c] = (z[jj] - mu) * rs * lng[c] + lnb[c];
    }
}

// hid = relu(b1 + sum_{kc<4} h1p[kc])   grid=64
__global__ __launch_bounds__(256) void hred(
    const float* __restrict__ h1p, const float* __restrict__ b1,
    float* __restrict__ hid)
{
    int b = blockIdx.x >> 2;
    int c = (blockIdx.x & 3) * 256 + threadIdx.x;
    float s = b1[c];
#pragma unroll
    for (int kc = 0; kc < 4; ++kc)
        s += h1p[(long)kc * 16 * F_ + (long)b * F_ + c];
    hid[(long)b * F_ + c] = fmaxf(s, 0.f);
}

// out = b2 + sum_{kc<8} op[kc]   grid=32
__global__ __launch_bounds__(256) void ored(
    const float* __restrict__ op, const float* __restrict__ b2,
    float* __restrict__ out)
{
    int b = blockIdx.x >> 1;
    int c = (blockIdx.x & 1) * 256 + threadIdx.x;
    float s = b2[c];
#pragma unroll
    for (int kc = 0; kc < 8; ++kc)
        s += op[(long)kc * 16 * H_ + (long)b * H_ + c];
    out[(long)b * H_ + c] = s;
}

// ---------------------------------------------------------------------------
extern "C" void kernel_launch(void* const* d_in, const int* in_sizes, int n_in,
                              void* d_out, int out_size, void* d_ws, size_t ws_size,
                              hipStream_t stream) {
    const float* x    = (const float*)d_in[0];
    const float* We   = (const float*)d_in[1];
    const float* be   = (const float*)d_in[2];
    const float* Wb   = (const float*)d_in[3];
    const float* Amat = (const float*)d_in[4];
    const float* Wr   = (const float*)d_in[5];
    const float* br   = (const float*)d_in[6];
    const float* lng  = (const float*)d_in[7];
    const float* lnb  = (const float*)d_in[8];
    const float* W1   = (const float*)d_in[9];
    const float* b1   = (const float*)d_in[10];
    const float* W2   = (const float*)d_in[11];
    const float* b2   = (const float*)d_in[12];
    float* out = (float*)d_out;

    float* ws  = (float*)d_ws;
    float* Wc  = ws;                         // 129 x 512
    float* V0  = Wc + 129 * H_;              // 2048 x 512
    float* V1  = V0 + 2048 * H_;             // 1024 x 512
    float* P2  = V1 + 1024 * H_;             // A^2
    float* P4  = P2 + H_ * H_;               // A^4
    float* P8  = P4 + H_ * H_;               // A^8
    float* P16 = P8 + H_ * H_;               // A^16
    float* P32 = P16 + H_ * H_;              // A^32
    float* P64 = P32 + H_ * H_;              // A^64
    float* P96 = P64 + H_ * H_;              // A^96
    float* zn  = P96 + H_ * H_;              // 16 x 512
    float* hid = zn + B_ * H_;               // 16 x 1024
    float* zp  = hid + B_ * F_;              // 13 x 16 x 512
    float* h1p = zp + 13 * B_ * H_;          // 4 x 16 x 1024
    float* op  = h1p + 4 * B_ * F_;          // 8 x 16 x 512

    // K0: Wc = [We;be]@Wb (129x512,K=256) [40] || A^2 [128]
    dual<<<168, 256, 0, stream>>>(We, be, Wb, nullptr, nullptr, Wc,
                                  129, M_, M_, H_, H_, 0, 3, 8, 40,
                                  Amat, Amat, P2);
    // K1: V0 = gather(x)@Wc + bc (2048x512,K=128) [512] || A^4 [128]
    dual<<<640, 256, 0, stream>>>(x, nullptr, Wc, Wc + 128 * H_, nullptr, V0,
                                  2048, L_, L_, H_, H_, 1, 1, 8, 512,
                                  P2, P2, P4);
    // K2 (l1): V1 = comb(V0, A), 1024 rows [256] || A^8 [128]
    dual<<<384, 256, 0, stream>>>(V0, nullptr, Amat, nullptr, V0, V1,
                                  1024, H_, H_, H_, H_, 0, 2, 8, 256,
                                  P4, P4, P8);
    // K3 (l2): V0 = comb(V1, A^2), 512 rows [128] || A^16 [128]
    dual<<<256, 256, 0, stream>>>(V1, nullptr, P2, nullptr, V1, V0,
                                  512, H_, H_, H_, H_, 0, 2, 8, 128,
                                  P8, P8, P16);
    // K4 (l3): V1 = comb(V0, A^4), 256 rows [64] || A^32 [128]
    dual<<<192, 256, 0, stream>>>(V0, nullptr, P4, nullptr, V0, V1,
                                  256, H_, H_, H_, H_, 0, 2, 8, 64,
                                  P16, P16, P32);
    // K5 (l4): V0 = comb(V1, A^8), 128 rows [32] || A^64 [128]
    dual<<<160, 256, 0, stream>>>(V1, nullptr, P8, nullptr, V1, V0,
                                  128, H_, H_, H_, H_, 0, 2, 8, 32,
                                  P32, P32, P64);
    // K6 (l5): V1 = comb(V0, A^16), 64 rows (4 nodes) [16] || A^96 = A^32*A^64 [128]
    dual<<<144, 256, 0, stream>>>(V0, nullptr, P16, nullptr, V0, V1,
                                  64, H_, H_, H_, H_, 0, 2, 8, 16,
                                  P32, P64, P96);
    // K7: z-partials (K=1664, 13 chunks x 8 col tiles)
    tailgemm<0><<<104, 256, 0, stream>>>(V1, x, P32, P64, P96, Wr, zp, 8, 128);
    // K7b: z reduce + LayerNorm -> zn
    zlnred<<<16, 256, 0, stream>>>(V1, zp, br, lng, lnb, zn);
    // K8: MLP1 partials (K=512, 4 chunks x 16 col tiles)
    tailgemm<1><<<64, 256, 0, stream>>>(zn, nullptr, nullptr, nullptr, nullptr,
                                        W1, h1p, 16, 128);
    // K8b: relu-reduce -> hid
    hred<<<64, 256, 0, stream>>>(h1p, b1, hid);
    // K9: MLP2 partials (K=1024, 8 chunks x 8 col tiles)
    tailgemm<2><<<64, 256, 0, stream>>>(hid, nullptr, nullptr, nullptr, nullptr,
                                        W2, op, 8, 128);
    // K9b: reduce -> out
    ored<<<32, 256, 0, stream>>>(op, b2, out);
}